// Round 8
// baseline (220.581 us; speedup 1.0000x reference)
//
#include <hip/hip_runtime.h>
#include <hip/hip_bf16.h>
#include <math.h>

#define B_  256
#define T_  512
#define D_  256
#define A_  50
#define EPS 1e-7f
#define NW  16   // waves per block

typedef short  short8  __attribute__((ext_vector_type(8)));
typedef float  floatx4 __attribute__((ext_vector_type(4)));

__device__ inline unsigned short f2bf(float f) {
    unsigned int u = __float_as_uint(f);
    u = (u + 0x7fffu + ((u >> 16) & 1u)) >> 16;   // RNE (inputs are finite)
    return (unsigned short)u;
}

// ---------------------------------------------------------------------------
// Prep: swizzle W [256][50] fp32 into bf16 B-fragment order for
// mfma_f32_16x16x32_bf16, zero-padded to N=64. Fragment (nt,ks), lane l,
// element j holds B[k][n] with n = nt*16 + (l&15), k = ks*32 + (l>>4)*8 + j.
// Layout: Wf[((nt*8+ks)*64 + l)*8 + j]. Also bias/u zero-padded to 64
// (u pad = 0 kills the fake columns in the epilogue dot).
// ---------------------------------------------------------------------------
__global__ void prep_kernel(const float* __restrict__ W,
                            const float* __restrict__ bias,
                            const float* __restrict__ u,
                            unsigned short* __restrict__ Wf,
                            float* __restrict__ bu64)
{
    int idx = blockIdx.x * 256 + threadIdx.x;      // 0 .. 16383
    int j  = idx & 7;
    int l  = (idx >> 3) & 63;
    int ks = (idx >> 9) & 7;
    int nt = idx >> 12;
    int n  = nt * 16 + (l & 15);
    int k  = ks * 32 + (l >> 4) * 8 + j;
    float val = (n < A_) ? W[k * A_ + n] : 0.0f;
    Wf[idx] = f2bf(val);
    if (idx < 64) {
        bu64[idx]      = (idx < A_) ? bias[idx] : 0.0f;
        bu64[64 + idx] = (idx < A_) ? u[idx]    : 0.0f;
    }
}

// pack 4 floats -> 4 bf16 (hardware v_cvt_pk_bf16_f32, RNE)
__device__ inline void pack_bf4(short8& av, int base, float fx, float fy,
                                float fz, float fw)
{
    union { __hip_bfloat162 h2; int i; } c0, c1;
    c0.h2 = __float22bfloat162_rn(make_float2(fx, fy));
    c1.h2 = __float22bfloat162_rn(make_float2(fz, fw));
    union { int i[4]; short8 s8; } pk;   // build two lanes-pairs
    // write through shorts to keep it simple & exact:
    av[base + 0] = (short)(c0.i & 0xffff);
    av[base + 1] = (short)((unsigned)c0.i >> 16);
    av[base + 2] = (short)(c1.i & 0xffff);
    av[base + 3] = (short)((unsigned)c1.i >> 16);
    (void)pk;
}

// ---------------------------------------------------------------------------
// Fused kernel: one block per batch (256 blocks x 1024 threads, 16 waves).
// Phase 1 (MFMA scores, m89-verified C layout col=l&15,row=quad*4+r):
//   wave w, pass p owns rows p*256 + w*16 .. +16. KEY CHANGE vs R7: all 16
//   A-fragment float4s for the pass are preloaded into registers BEFORE the
//   ks loop -> 16 independent HBM loads in flight per wave (R7's 64-VGPR
//   compile serialized them ~2 deep -> 1.7 TB/s). launch_bounds(1024,4)
//   allows 128 VGPRs. bf16 convert via hardware v_cvt_pk_bf16_f32.
// Sum: LDS tree over 512 scores -> inv.
// Phase 2: wave w pools t in [w*32,+32): 1KB coalesced loads of x_b
//   (L3-hot; R7 FETCH=134MB proved the re-read doesn't touch HBM).
// ---------------------------------------------------------------------------
__global__ __launch_bounds__(1024, 4)
void fused_kernel(const float* __restrict__ x,
                  const unsigned short* __restrict__ Wf,
                  const float* __restrict__ bu64,
                  float* __restrict__ out)
{
    __shared__ float s_lds[T_];
    __shared__ float part[NW * 256];   // 16 KB (also reduction scratch)

    const int tid  = threadIdx.x;
    const int w    = tid >> 6;
    const int l    = tid & 63;
    const int c    = l & 15;        // A-row / C-col within tile
    const int quad = l >> 4;        // k-slice / C-row-group
    const int bb   = blockIdx.x;

    const float*  __restrict__ xb  = x + (size_t)bb * T_ * D_;
    const short8* __restrict__ wf8 = (const short8*)Wf;

    float bnc[4], unc[4];
    #pragma unroll
    for (int nt = 0; nt < 4; nt++) {
        bnc[nt] = bu64[nt * 16 + c];
        unc[nt] = bu64[64 + nt * 16 + c];
    }

    // ---- Phase 1: scores ----
    #pragma unroll
    for (int pass = 0; pass < 2; pass++) {
        const int rowbase = pass * 256 + w * 16;
        const float4* __restrict__ xrow =
            (const float4*)(xb + (size_t)(rowbase + c) * D_);

        // Preload the lane's entire 256B of A data: 16 independent loads.
        float4 pre[16];
        #pragma unroll
        for (int i = 0; i < 16; i++)
            pre[i] = xrow[(i >> 1) * 8 + quad * 2 + (i & 1)];

        floatx4 acc[4];
        #pragma unroll
        for (int nt = 0; nt < 4; nt++) acc[nt] = (floatx4){0.f, 0.f, 0.f, 0.f};

        #pragma unroll
        for (int ks = 0; ks < 8; ks++) {
            const float4 a0 = pre[2 * ks];
            const float4 a1 = pre[2 * ks + 1];
            short8 av;
            pack_bf4(av, 0, a0.x, a0.y, a0.z, a0.w);
            pack_bf4(av, 4, a1.x, a1.y, a1.z, a1.w);
            #pragma unroll
            for (int nt = 0; nt < 4; nt++) {
                const short8 bv = wf8[(nt * 8 + ks) * 64 + l];
                acc[nt] = __builtin_amdgcn_mfma_f32_16x16x32_bf16(av, bv, acc[nt], 0, 0, 0);
            }
        }

        #pragma unroll
        for (int r = 0; r < 4; r++) {
            float v = 0.0f;
            #pragma unroll
            for (int nt = 0; nt < 4; nt++)
                v += tanhf(acc[nt][r] + bnc[nt]) * unc[nt];
            #pragma unroll
            for (int off = 1; off < 16; off <<= 1)
                v += __shfl_xor(v, off, 16);
            if (c == 0)
                s_lds[rowbase + quad * 4 + r] = expf(v);
        }
    }
    __syncthreads();

    // ---- Sum of exp-scores -> inv (LDS tree in part[]) ----
    if (tid < 512) part[tid] = s_lds[tid];
    __syncthreads();
    for (int off = 256; off > 0; off >>= 1) {
        if (tid < off) part[tid] += part[tid + off];
        __syncthreads();
    }
    const float inv = 1.0f / (part[0] + EPS);
    __syncthreads();   // everyone has read part[0] before part is reused

    // ---- Phase 2: weighted pool (x_b re-read is L3-hot) ----
    float4 acc2 = make_float4(0.f, 0.f, 0.f, 0.f);
    const int t0 = w * 32;
    #pragma unroll
    for (int i = 0; i < 32; i++) {
        const float4 xv = *(const float4*)(xb + (size_t)(t0 + i) * D_ + l * 4);
        const float sv  = s_lds[t0 + i];   // wave-uniform -> LDS broadcast
        acc2.x += xv.x * sv;
        acc2.y += xv.y * sv;
        acc2.z += xv.z * sv;
        acc2.w += xv.w * sv;
    }
    acc2.x *= inv; acc2.y *= inv; acc2.z *= inv; acc2.w *= inv;

    part[w * 256 + l * 4 + 0] = acc2.x;
    part[w * 256 + l * 4 + 1] = acc2.y;
    part[w * 256 + l * 4 + 2] = acc2.z;
    part[w * 256 + l * 4 + 3] = acc2.w;
    __syncthreads();

    if (tid < 256) {
        float o = 0.0f;
        #pragma unroll
        for (int wv = 0; wv < NW; wv++) o += part[wv * 256 + tid];
        out[(size_t)bb * 256 + tid] = o;
    }
}

// ---------------------------------------------------------------------------
extern "C" void kernel_launch(void* const* d_in, const int* in_sizes, int n_in,
                              void* d_out, int out_size, void* d_ws, size_t ws_size,
                              hipStream_t stream)
{
    const float* x = (const float*)d_in[0];
    const float* W = (const float*)d_in[1];
    const float* b = (const float*)d_in[2];
    const float* u = (const float*)d_in[3];

    unsigned short* Wf  = (unsigned short*)d_ws;          // 16384 u16
    float*         bu64 = (float*)(Wf + 16384);           // 128 f
    float*         out  = (float*)d_out;

    prep_kernel  <<<64,  256,  0, stream>>>(W, b, u, Wf, bu64);
    fused_kernel <<<B_,  1024, 0, stream>>>(x, Wf, bu64, out);
}

// Round 9
// 218.776 us; speedup vs baseline: 1.0083x; 1.0083x over previous
//
#include <hip/hip_runtime.h>
#include <hip/hip_bf16.h>
#include <math.h>

#define B_  256
#define T_  512
#define D_  256
#define A_  50
#define EPS 1e-7f
#define NW  16   // waves per block

typedef short  short8  __attribute__((ext_vector_type(8)));
typedef float  floatx4 __attribute__((ext_vector_type(4)));

__device__ inline unsigned short f2bf(float f) {
    unsigned int u = __float_as_uint(f);
    u = (u + 0x7fffu + ((u >> 16) & 1u)) >> 16;   // RNE (inputs are finite)
    return (unsigned short)u;
}

// ---------------------------------------------------------------------------
// Prep: swizzle W [256][50] fp32 into bf16 B-fragment order for
// mfma_f32_16x16x32_bf16, zero-padded to N=64. Fragment (nt,ks), lane l,
// element j holds B[k][n] with n = nt*16 + (l&15), k = ks*32 + (l>>4)*8 + j.
// Layout: Wf[((nt*8+ks)*64 + l)*8 + j]. Also bias/u zero-padded to 64.
// ---------------------------------------------------------------------------
__global__ void prep_kernel(const float* __restrict__ W,
                            const float* __restrict__ bias,
                            const float* __restrict__ u,
                            unsigned short* __restrict__ Wf,
                            float* __restrict__ bu64)
{
    int idx = blockIdx.x * 256 + threadIdx.x;      // 0 .. 16383
    int j  = idx & 7;
    int l  = (idx >> 3) & 63;
    int ks = (idx >> 9) & 7;
    int nt = idx >> 12;
    int n  = nt * 16 + (l & 15);
    int k  = ks * 32 + (l >> 4) * 8 + j;
    float val = (n < A_) ? W[k * A_ + n] : 0.0f;
    Wf[idx] = f2bf(val);
    if (idx < 64) {
        bu64[idx]      = (idx < A_) ? bias[idx] : 0.0f;
        bu64[64 + idx] = (idx < A_) ? u[idx]    : 0.0f;
    }
}

// pack 4 floats -> 4 bf16 (hardware v_cvt_pk_bf16_f32, RNE)
__device__ inline void pack_bf4(short8& av, int base, float fx, float fy,
                                float fz, float fw)
{
    union { __hip_bfloat162 h2; int i; } c0, c1;
    c0.h2 = __float22bfloat162_rn(make_float2(fx, fy));
    c1.h2 = __float22bfloat162_rn(make_float2(fz, fw));
    av[base + 0] = (short)(c0.i & 0xffff);
    av[base + 1] = (short)((unsigned)c0.i >> 16);
    av[base + 2] = (short)(c1.i & 0xffff);
    av[base + 3] = (short)((unsigned)c1.i >> 16);
}

// ---------------------------------------------------------------------------
// Fused kernel: one block per batch (256 blocks x 1024 threads, 16 waves).
// R9 changes vs R8 (both aimed at the mixed-vmcnt serialization seen in
// R7/R8 counters — hbm stuck at 1.4-1.7 TB/s, VGPR stuck at 64):
//  1. Wf is staged to LDS once per block. B-fragment reads become
//     ds_read_b128 on the *lgkmcnt* counter, so the vmcnt queue holds ONLY
//     the HBM A-loads — a fast B wait can no longer force slow A drains.
//  2. amdgpu_waves_per_eu(4,4) pins exactly 1 block/CU, so the register
//     allocator must use the 128-VGPR budget instead of targeting 8
//     waves/EU at 64 VGPR; pre[16] (64 VGPRs) now actually stays resident:
//     16 independent 1KB/wave HBM loads in flight.
// Phase 1 (m89-verified C layout col=l&15,row=quad*4+r) -> exp scores in
// LDS; LDS tree sum -> inv; Phase 2 pools x_b (L3-hot, proven by R7
// FETCH=134MB) with 32 coalesced 1KB loads/wave.
// ---------------------------------------------------------------------------
__global__ __launch_bounds__(1024)
__attribute__((amdgpu_waves_per_eu(4, 4)))
void fused_kernel(const float* __restrict__ x,
                  const unsigned short* __restrict__ Wf,
                  const float* __restrict__ bu64,
                  float* __restrict__ out)
{
    __shared__ int4  Wl[2048];         // 32 KB: Wf staged, fragment order
    __shared__ float s_lds[T_];
    __shared__ float part[NW * 256];   // 16 KB (also reduction scratch)

    const int tid  = threadIdx.x;
    const int w    = tid >> 6;
    const int l    = tid & 63;
    const int c    = l & 15;        // A-row / C-col within tile
    const int quad = l >> 4;        // k-slice / C-row-group
    const int bb   = blockIdx.x;

    // Stage Wf -> LDS (32 KB, coalesced int4)
    {
        const int4* __restrict__ wsrc = (const int4*)Wf;
        Wl[tid]        = wsrc[tid];
        Wl[tid + 1024] = wsrc[tid + 1024];
    }

    const float*  __restrict__ xb  = x + (size_t)bb * T_ * D_;
    const short8* __restrict__ wl8 = (const short8*)Wl;

    float bnc[4], unc[4];
    #pragma unroll
    for (int nt = 0; nt < 4; nt++) {
        bnc[nt] = bu64[nt * 16 + c];
        unc[nt] = bu64[64 + nt * 16 + c];
    }
    __syncthreads();   // Wl ready

    // ---- Phase 1: scores ----
    #pragma unroll
    for (int pass = 0; pass < 2; pass++) {
        const int rowbase = pass * 256 + w * 16;
        const float4* __restrict__ xrow =
            (const float4*)(xb + (size_t)(rowbase + c) * D_);

        // Preload the lane's entire 256B of A data: 16 independent HBM loads.
        float4 pre[16];
        #pragma unroll
        for (int i = 0; i < 16; i++)
            pre[i] = xrow[(i >> 1) * 8 + quad * 2 + (i & 1)];

        floatx4 acc[4];
        #pragma unroll
        for (int nt = 0; nt < 4; nt++) acc[nt] = (floatx4){0.f, 0.f, 0.f, 0.f};

        #pragma unroll
        for (int ks = 0; ks < 8; ks++) {
            const float4 a0 = pre[2 * ks];
            const float4 a1 = pre[2 * ks + 1];
            short8 av;
            pack_bf4(av, 0, a0.x, a0.y, a0.z, a0.w);
            pack_bf4(av, 4, a1.x, a1.y, a1.z, a1.w);
            #pragma unroll
            for (int nt = 0; nt < 4; nt++) {
                const short8 bv = wl8[(nt * 8 + ks) * 64 + l];  // ds_read_b128
                acc[nt] = __builtin_amdgcn_mfma_f32_16x16x32_bf16(av, bv, acc[nt], 0, 0, 0);
            }
        }

        #pragma unroll
        for (int r = 0; r < 4; r++) {
            float v = 0.0f;
            #pragma unroll
            for (int nt = 0; nt < 4; nt++)
                v += tanhf(acc[nt][r] + bnc[nt]) * unc[nt];
            #pragma unroll
            for (int off = 1; off < 16; off <<= 1)
                v += __shfl_xor(v, off, 16);
            if (c == 0)
                s_lds[rowbase + quad * 4 + r] = expf(v);
        }
    }
    __syncthreads();

    // ---- Sum of exp-scores -> inv (LDS tree in part[]) ----
    if (tid < 512) part[tid] = s_lds[tid];
    __syncthreads();
    for (int off = 256; off > 0; off >>= 1) {
        if (tid < off) part[tid] += part[tid + off];
        __syncthreads();
    }
    const float inv = 1.0f / (part[0] + EPS);
    __syncthreads();   // everyone has read part[0] before part is reused

    // ---- Phase 2: weighted pool (x_b re-read is L3-hot) ----
    float4 acc2 = make_float4(0.f, 0.f, 0.f, 0.f);
    const int t0 = w * 32;
    #pragma unroll
    for (int i = 0; i < 32; i++) {
        const float4 xv = *(const float4*)(xb + (size_t)(t0 + i) * D_ + l * 4);
        const float sv  = s_lds[t0 + i];   // wave-uniform -> LDS broadcast
        acc2.x += xv.x * sv;
        acc2.y += xv.y * sv;
        acc2.z += xv.z * sv;
        acc2.w += xv.w * sv;
    }
    acc2.x *= inv; acc2.y *= inv; acc2.z *= inv; acc2.w *= inv;

    part[w * 256 + l * 4 + 0] = acc2.x;
    part[w * 256 + l * 4 + 1] = acc2.y;
    part[w * 256 + l * 4 + 2] = acc2.z;
    part[w * 256 + l * 4 + 3] = acc2.w;
    __syncthreads();

    if (tid < 256) {
        float o = 0.0f;
        #pragma unroll
        for (int wv = 0; wv < NW; wv++) o += part[wv * 256 + tid];
        out[(size_t)bb * 256 + tid] = o;
    }
}

// ---------------------------------------------------------------------------
extern "C" void kernel_launch(void* const* d_in, const int* in_sizes, int n_in,
                              void* d_out, int out_size, void* d_ws, size_t ws_size,
                              hipStream_t stream)
{
    const float* x = (const float*)d_in[0];
    const float* W = (const float*)d_in[1];
    const float* b = (const float*)d_in[2];
    const float* u = (const float*)d_in[3];

    unsigned short* Wf  = (unsigned short*)d_ws;          // 16384 u16
    float*         bu64 = (float*)(Wf + 16384);           // 128 f
    float*         out  = (float*)d_out;

    prep_kernel  <<<64,  256,  0, stream>>>(W, b, u, Wf, bu64);
    fused_kernel <<<B_,  1024, 0, stream>>>(x, Wf, bu64, out);
}